// Round 6
// baseline (135.771 us; speedup 1.0000x reference)
//
#include <hip/hip_runtime.h>

constexpr int HH = 100;
constexpr int WW = 100;
constexpr int NH = 8;
constexpr int NP = 4;
constexpr int B  = 4;
constexpr int Q  = HH * WW;   // 10000
constexpr int S  = Q;
constexpr int K  = 256;
constexpr int DH = 32;

typedef __attribute__((ext_vector_type(8))) short short8;
typedef __attribute__((ext_vector_type(4))) short short4_v;
typedef __attribute__((ext_vector_type(4))) float f32x4;

struct __align__(8) ushort4_t { unsigned short x, y, z, w; };

__device__ inline unsigned short f2bf(float f) {
    unsigned u = __builtin_bit_cast(unsigned, f);
    u += 0x7fffu + ((u >> 16) & 1u);          // RNE
    return (unsigned short)(u >> 16);
}
__device__ inline float bf2f(unsigned short h) {
    return __builtin_bit_cast(float, ((unsigned)h) << 16);
}
__device__ inline unsigned short f2h(float f) {
    _Float16 h = (_Float16)f;
    return __builtin_bit_cast(unsigned short, h);
}
__device__ inline float h2f(unsigned short u) {
    return (float)__builtin_bit_cast(_Float16, u);
}

// LDS bf16 tile helpers, XOR-swizzled (flips element-index bits 3..5 by row&7)
__device__ inline void lds_st16s(short* base, int row, int stride, int kcol, short8 v) {
    *reinterpret_cast<short8*>(&base[row * stride + (kcol ^ ((row & 7) << 3))]) = v;
}
__device__ inline short8 lds_ld16s(const short* base, int row, int stride, int kcol) {
    return *reinterpret_cast<const short8*>(&base[row * stride + (kcol ^ ((row & 7) << 3))]);
}

__device__ inline short8 cvt8(float4 a, float4 b) {
    short8 r;
    r[0] = (short)f2bf(a.x); r[1] = (short)f2bf(a.y);
    r[2] = (short)f2bf(a.z); r[3] = (short)f2bf(a.w);
    r[4] = (short)f2bf(b.x); r[5] = (short)f2bf(b.y);
    r[6] = (short)f2bf(b.z); r[7] = (short)f2bf(b.w);
    return r;
}

// ---------------------------------------------------------------------------
// Kernel 1: value projection  enc[B*S][256] @ W_val^T + b_val -> vflat bf16
// Tile 32 x 256 (full N), 512 threads, 1250 blocks -> 4 blocks/CU.
// ---------------------------------------------------------------------------
__global__ __launch_bounds__(512) void value_proj(
    const float* __restrict__ enc, const float* __restrict__ Wv,
    const float* __restrict__ bv, unsigned short* __restrict__ vflat)
{
    __shared__ short As[32 * 64];
    __shared__ short Bs[256 * 64];

    const int tid = threadIdx.x;
    const int m0  = blockIdx.x * 32;
    const int lane = tid & 63, w = tid >> 6;
    const int l15 = lane & 15, l4 = lane >> 4;

    const int arow = tid >> 4, ak4 = (tid & 15) * 4;   // A staging: 4 el/thread
    const int brow = tid >> 1, bk32 = (tid & 1) * 32;  // B staging: 32 el/thread

    f32x4 acc[2][2];
#pragma unroll
    for (int i = 0; i < 2; ++i)
#pragma unroll
        for (int j = 0; j < 2; ++j) acc[i][j] = f32x4{0.f, 0.f, 0.f, 0.f};

    for (int k0 = 0; k0 < K; k0 += 64) {
        {
            float4 f = *reinterpret_cast<const float4*>(
                &enc[(size_t)(m0 + arow) * K + k0 + ak4]);
            short4_v s;
            s[0] = (short)f2bf(f.x); s[1] = (short)f2bf(f.y);
            s[2] = (short)f2bf(f.z); s[3] = (short)f2bf(f.w);
            *reinterpret_cast<short4_v*>(&As[arow * 64 + (ak4 ^ ((arow & 7) << 3))]) = s;
        }
        {
            const float* src = &Wv[(size_t)brow * K + k0 + bk32];
#pragma unroll
            for (int c = 0; c < 4; ++c) {
                float4 f0 = *reinterpret_cast<const float4*>(src + c * 8);
                float4 f1 = *reinterpret_cast<const float4*>(src + c * 8 + 4);
                lds_st16s(Bs, brow, 64, bk32 + c * 8, cvt8(f0, f1));
            }
        }
        __syncthreads();
#pragma unroll
        for (int kk = 0; kk < 2; ++kk) {
            const int kc = kk * 32 + l4 * 8;
            short8 a0 = lds_ld16s(As, l15, 64, kc);
            short8 a1 = lds_ld16s(As, 16 + l15, 64, kc);
#pragma unroll
            for (int nf = 0; nf < 2; ++nf) {
                short8 bb = lds_ld16s(Bs, w * 32 + nf * 16 + l15, 64, kc);
                acc[0][nf] = __builtin_amdgcn_mfma_f32_16x16x32_bf16(a0, bb, acc[0][nf], 0, 0, 0);
                acc[1][nf] = __builtin_amdgcn_mfma_f32_16x16x32_bf16(a1, bb, acc[1][nf], 0, 0, 0);
            }
        }
        __syncthreads();
    }

#pragma unroll
    for (int nf = 0; nf < 2; ++nf) {
        const int n = w * 32 + nf * 16 + l15;
        const float bias = bv[n];
        const int h = n >> 5, dd = n & 31;
#pragma unroll
        for (int mf = 0; mf < 2; ++mf) {
#pragma unroll
            for (int r = 0; r < 4; ++r) {
                const int m = m0 + mf * 16 + l4 * 4 + r;
                const int b = m / S, s = m - (m / S) * S;
                vflat[(((size_t)(b * NH + h)) * S + s) * DH + dd] =
                    f2bf(acc[mf][nf][r] + bias);
            }
        }
    }
}

// ---------------------------------------------------------------------------
// Kernel 2: fused {off+attn proj -> softmax+coords -> bilinear gather} -> tmp
// One block per 32 q-rows. 512 threads = 8 waves. Grid 1250, XCD-swizzled.
// LDS (28,672 B): As[32x64] 4KB + Bs[96x64] 12KB (phase 1);
//                 P f16 [32][104] 6.7KB aliases As/Bs (post-GEMM);
//                 cidx 4KB @16384; cw 8KB @20480.
// ---------------------------------------------------------------------------
__global__ __launch_bounds__(512) void proj_sample(
    const float* __restrict__ hidden, const float* __restrict__ W_off,
    const float* __restrict__ W_attn, const float* __restrict__ b_off,
    const float* __restrict__ b_attn, const float* __restrict__ ref,
    const unsigned short* __restrict__ vflat,
    unsigned short* __restrict__ tmp)
{
    __shared__ char smem[28672];
    short* As = (short*)smem;                       // [32][64]
    short* Bs = (short*)(smem + 4096);              // [96][64]
    unsigned short* P = (unsigned short*)smem;      // [32][104] f16 (aliases As/Bs)
    unsigned int* cidx = (unsigned int*)(smem + 16384);   // 1024 u32
    uint2* cw = (uint2*)(smem + 20480);                   // 1024 uint2

    // bijective chunked XCD swizzle (nwg = 1250 = 8*156+2)
    const int nwg = gridDim.x;
    const int q8 = nwg >> 3, r8 = nwg & 7;
    const int xcd = blockIdx.x & 7, pos = blockIdx.x >> 3;
    const int start = (xcd < r8) ? xcd * (q8 + 1) : r8 * (q8 + 1) + (xcd - r8) * q8;
    const int m0 = (start + pos) * 32;

    const int tid = threadIdx.x;
    const int lane = tid & 63, w = tid >> 6;
    const int l15 = lane & 15, l4 = lane >> 4;

    // ---------------- phase 1: P = hidden_tile @ [W_off;W_attn]^T ----------
    const int arow = tid >> 4, ak4 = (tid & 15) * 4;      // A: 4 f32/thread
    const int br0 = tid >> 3, bk8 = (tid & 7) * 8;        // B rows 0..63: 8 f32
    const bool bs2 = (tid < 256);
    const int br1 = 64 + (tid >> 3);                      // B rows 64..95 (tid<256)

    f32x4 acc1[2];
    acc1[0] = f32x4{0.f, 0.f, 0.f, 0.f};
    acc1[1] = f32x4{0.f, 0.f, 0.f, 0.f};
    const int nb1 = w * 16;     // waves 0..5 compute; 6,7 stage only

    float4 fa, fb0a, fb0b, fb1a, fb1b;
    auto ld1 = [&](int k0) {
        fa = *reinterpret_cast<const float4*>(
            &hidden[(size_t)(m0 + arow) * K + k0 + ak4]);
        const float* s0 = &W_off[(size_t)br0 * K + k0 + bk8];
        fb0a = *reinterpret_cast<const float4*>(s0);
        fb0b = *reinterpret_cast<const float4*>(s0 + 4);
        if (bs2) {
            const float* s1 = &W_attn[(size_t)(br1 - 64) * K + k0 + bk8];
            fb1a = *reinterpret_cast<const float4*>(s1);
            fb1b = *reinterpret_cast<const float4*>(s1 + 4);
        }
    };
    auto wr1 = [&]() {
        short4_v s;
        s[0] = (short)f2bf(fa.x); s[1] = (short)f2bf(fa.y);
        s[2] = (short)f2bf(fa.z); s[3] = (short)f2bf(fa.w);
        *reinterpret_cast<short4_v*>(&As[arow * 64 + (ak4 ^ ((arow & 7) << 3))]) = s;
        lds_st16s(Bs, br0, 64, bk8, cvt8(fb0a, fb0b));
        if (bs2) lds_st16s(Bs, br1, 64, bk8, cvt8(fb1a, fb1b));
    };

    ld1(0);
    for (int k0 = 0; k0 < K; k0 += 64) {
        wr1();
        __syncthreads();
        if (k0 < K - 64) ld1(k0 + 64);
        if (w < 6) {
#pragma unroll
            for (int kk = 0; kk < 2; ++kk) {
                const int kc = kk * 32 + l4 * 8;
                short8 a0 = lds_ld16s(As, l15, 64, kc);
                short8 a1 = lds_ld16s(As, 16 + l15, 64, kc);
                short8 bb = lds_ld16s(Bs, nb1 + l15, 64, kc);
                acc1[0] = __builtin_amdgcn_mfma_f32_16x16x32_bf16(a0, bb, acc1[0], 0, 0, 0);
                acc1[1] = __builtin_amdgcn_mfma_f32_16x16x32_bf16(a1, bb, acc1[1], 0, 0, 0);
            }
        }
        __syncthreads();
    }
    if (w < 6) {
        const int col = nb1 + l15;
        const float bias = (col < 64) ? b_off[col] : b_attn[col - 64];
#pragma unroll
        for (int mf = 0; mf < 2; ++mf)
#pragma unroll
            for (int r = 0; r < 4; ++r) {
                const int row = mf * 16 + l4 * 4 + r;
                P[row * 104 + col] = f2h(acc1[mf][r] + bias);
            }
    }
    __syncthreads();

    // ---------------- phase 2a: softmax + corner coords/weights ------------
    if (tid < 256) {
        const int r = tid >> 3, h = tid & 7;
        const int m = m0 + r;
        const float refx = ref[(size_t)m * 2 + 0];
        const float refy = ref[(size_t)m * 2 + 1];
        float l[NP];
#pragma unroll
        for (int p = 0; p < NP; ++p) l[p] = h2f(P[r * 104 + 64 + h * 4 + p]);
        const float mx = fmaxf(fmaxf(l[0], l[1]), fmaxf(l[2], l[3]));
        float e[NP]; float esum = 0.f;
#pragma unroll
        for (int p = 0; p < NP; ++p) { e[p] = __expf(l[p] - mx); esum += e[p]; }
        const float inv = 1.f / esum;
#pragma unroll
        for (int p = 0; p < NP; ++p) {
            const float ox = h2f(P[r * 104 + h * 8 + p * 2 + 0]);
            const float oy = h2f(P[r * 104 + h * 8 + p * 2 + 1]);
            const float x = fmaf(refx, (float)WW, ox) - 0.5f;
            const float y = fmaf(refy, (float)HH, oy) - 0.5f;
            const float x0f = floorf(x), y0f = floorf(y);
            const float wx1 = x - x0f, wx0 = 1.f - wx1;
            const float wy1 = y - y0f, wy0 = 1.f - wy1;
            const int x0 = (int)x0f, y0 = (int)y0f;
            const bool vx0 = (x0 >= 0) && (x0 < WW);
            const bool vx1 = (x0 + 1 >= 0) && (x0 + 1 < WW);
            const bool vy0 = (y0 >= 0) && (y0 < HH);
            const bool vy1 = (y0 + 1 >= 0) && (y0 + 1 < HH);
            const int xi0 = min(max(x0, 0), WW - 1);
            const int xi1 = min(max(x0 + 1, 0), WW - 1);
            const int yi0 = min(max(y0, 0), HH - 1);
            const int yi1 = min(max(y0 + 1, 0), HH - 1);
            const float ap = e[p] * inv;
            const float c0 = ap * wx0 * wy0 * ((vx0 && vy0) ? 1.f : 0.f);
            const float c1 = ap * wx1 * wy0 * ((vx1 && vy0) ? 1.f : 0.f);
            const float c2 = ap * wx0 * wy1 * ((vx0 && vy1) ? 1.f : 0.f);
            const float c3 = ap * wx1 * wy1 * ((vx1 && vy1) ? 1.f : 0.f);
            const int trip = ((r * 8 + h) << 2) + p;
            cidx[trip] = (unsigned)xi0 | ((unsigned)xi1 << 8)
                       | ((unsigned)yi0 << 16) | ((unsigned)yi1 << 24);
            uint2 wv;
            wv.x = (unsigned)f2h(c0) | ((unsigned)f2h(c1) << 16);
            wv.y = (unsigned)f2h(c2) | ((unsigned)f2h(c3) << 16);
            cw[trip] = wv;
        }
    }
    __syncthreads();

    // ---------------- phase 2b: gather + accumulate -> tmp (global) --------
    {
        const int r = tid >> 4;               // 0..31
        const int d0 = (tid & 7) * 4;         // 8 d-groups of 4
        const int hh = (tid >> 3) & 1;        // h half: 0..3 or 4..7
        const int m = m0 + r;
        const int b = m / Q;
        float o[4][4];
#pragma unroll
        for (int hi = 0; hi < 4; ++hi)
#pragma unroll
            for (int c = 0; c < 4; ++c) o[hi][c] = 0.f;

#pragma unroll
        for (int hi = 0; hi < 4; ++hi) {
            const int h = hh * 4 + hi;
            const unsigned short* vb = vflat + (size_t)(b * NH + h) * (S * DH);
#pragma unroll
            for (int p = 0; p < NP; ++p) {
                const int trip = ((r * 8 + h) << 2) + p;
                const unsigned u = cidx[trip];
                const uint2 wv = cw[trip];
                const int xi0 = u & 255, xi1 = (u >> 8) & 255;
                const int yi0 = (u >> 16) & 255, yi1 = u >> 24;
                const float c0 = h2f((unsigned short)(wv.x & 0xffff));
                const float c1 = h2f((unsigned short)(wv.x >> 16));
                const float c2 = h2f((unsigned short)(wv.y & 0xffff));
                const float c3 = h2f((unsigned short)(wv.y >> 16));
                const ushort4_t v0 = *reinterpret_cast<const ushort4_t*>(&vb[(size_t)((yi0 * WW + xi0) * DH + d0)]);
                const ushort4_t v1 = *reinterpret_cast<const ushort4_t*>(&vb[(size_t)((yi0 * WW + xi1) * DH + d0)]);
                const ushort4_t v2 = *reinterpret_cast<const ushort4_t*>(&vb[(size_t)((yi1 * WW + xi0) * DH + d0)]);
                const ushort4_t v3 = *reinterpret_cast<const ushort4_t*>(&vb[(size_t)((yi1 * WW + xi1) * DH + d0)]);
                o[hi][0] = fmaf(c0, bf2f(v0.x), fmaf(c1, bf2f(v1.x), fmaf(c2, bf2f(v2.x), fmaf(c3, bf2f(v3.x), o[hi][0]))));
                o[hi][1] = fmaf(c0, bf2f(v0.y), fmaf(c1, bf2f(v1.y), fmaf(c2, bf2f(v2.y), fmaf(c3, bf2f(v3.y), o[hi][1]))));
                o[hi][2] = fmaf(c0, bf2f(v0.z), fmaf(c1, bf2f(v1.z), fmaf(c2, bf2f(v2.z), fmaf(c3, bf2f(v3.z), o[hi][2]))));
                o[hi][3] = fmaf(c0, bf2f(v0.w), fmaf(c1, bf2f(v1.w), fmaf(c2, bf2f(v2.w), fmaf(c3, bf2f(v3.w), o[hi][3]))));
            }
        }
#pragma unroll
        for (int hi = 0; hi < 4; ++hi) {
            const int h = hh * 4 + hi;
            ushort4_t ov;
            ov.x = f2bf(o[hi][0]); ov.y = f2bf(o[hi][1]);
            ov.z = f2bf(o[hi][2]); ov.w = f2bf(o[hi][3]);
            *reinterpret_cast<ushort4_t*>(&tmp[(size_t)m * 256 + h * 32 + d0]) = ov;
        }
    }
}

// ---------------------------------------------------------------------------
// Kernel 3: out projection  tmp[M][256] (bf16) @ W_out^T + b_out -> out f32
// Structural clone of value_proj; A is bf16 (no conversion).
// ---------------------------------------------------------------------------
__global__ __launch_bounds__(512) void out_proj(
    const unsigned short* __restrict__ tmp, const float* __restrict__ Wo,
    const float* __restrict__ bo, float* __restrict__ out)
{
    __shared__ short As[32 * 64];
    __shared__ short Bs[256 * 64];

    const int tid = threadIdx.x;
    const int m0  = blockIdx.x * 32;
    const int lane = tid & 63, w = tid >> 6;
    const int l15 = lane & 15, l4 = lane >> 4;

    const int arow = tid >> 4, ak4 = (tid & 15) * 4;
    const int brow = tid >> 1, bk32 = (tid & 1) * 32;

    f32x4 acc[2][2];
#pragma unroll
    for (int i = 0; i < 2; ++i)
#pragma unroll
        for (int j = 0; j < 2; ++j) acc[i][j] = f32x4{0.f, 0.f, 0.f, 0.f};

    for (int k0 = 0; k0 < K; k0 += 64) {
        {
            short4_v s = *reinterpret_cast<const short4_v*>(
                &tmp[(size_t)(m0 + arow) * K + k0 + ak4]);
            *reinterpret_cast<short4_v*>(&As[arow * 64 + (ak4 ^ ((arow & 7) << 3))]) = s;
        }
        {
            const float* src = &Wo[(size_t)brow * K + k0 + bk32];
#pragma unroll
            for (int c = 0; c < 4; ++c) {
                float4 f0 = *reinterpret_cast<const float4*>(src + c * 8);
                float4 f1 = *reinterpret_cast<const float4*>(src + c * 8 + 4);
                lds_st16s(Bs, brow, 64, bk32 + c * 8, cvt8(f0, f1));
            }
        }
        __syncthreads();
#pragma unroll
        for (int kk = 0; kk < 2; ++kk) {
            const int kc = kk * 32 + l4 * 8;
            short8 a0 = lds_ld16s(As, l15, 64, kc);
            short8 a1 = lds_ld16s(As, 16 + l15, 64, kc);
#pragma unroll
            for (int nf = 0; nf < 2; ++nf) {
                short8 bb = lds_ld16s(Bs, w * 32 + nf * 16 + l15, 64, kc);
                acc[0][nf] = __builtin_amdgcn_mfma_f32_16x16x32_bf16(a0, bb, acc[0][nf], 0, 0, 0);
                acc[1][nf] = __builtin_amdgcn_mfma_f32_16x16x32_bf16(a1, bb, acc[1][nf], 0, 0, 0);
            }
        }
        __syncthreads();
    }

#pragma unroll
    for (int nf = 0; nf < 2; ++nf) {
        const int n = w * 32 + nf * 16 + l15;
        const float bias = bo[n];
#pragma unroll
        for (int mf = 0; mf < 2; ++mf) {
#pragma unroll
            for (int r = 0; r < 4; ++r) {
                const int m = m0 + mf * 16 + l4 * 4 + r;
                out[(size_t)m * K + n] = acc[mf][nf][r] + bias;
            }
        }
    }
}

// ---------------------------------------------------------------------------
extern "C" void kernel_launch(void* const* d_in, const int* in_sizes, int n_in,
                              void* d_out, int out_size, void* d_ws, size_t ws_size,
                              hipStream_t stream)
{
    const float* hidden = (const float*)d_in[0];
    const float* enc    = (const float*)d_in[1];
    const float* refp   = (const float*)d_in[2];
    const float* W_off  = (const float*)d_in[4];
    const float* b_off  = (const float*)d_in[5];
    const float* W_attn = (const float*)d_in[6];
    const float* b_attn = (const float*)d_in[7];
    const float* W_val  = (const float*)d_in[8];
    const float* b_val  = (const float*)d_in[9];
    const float* W_out  = (const float*)d_in[10];
    const float* b_out  = (const float*)d_in[11];
    float* out = (float*)d_out;

    unsigned short* vflat = (unsigned short*)d_ws;               // 20.48 MB bf16
    unsigned short* tmp   = vflat + (size_t)B * NH * S * DH;     // 20.48 MB bf16

    const int M = B * Q;  // 40000

    // 1) value projection -> vflat bf16 [B*NH][S][32]
    value_proj<<<M / 32, 512, 0, stream>>>(enc, W_val, b_val, vflat);

    // 2) fused proj + softmax + bilinear gather -> tmp bf16 [M][256]
    proj_sample<<<M / 32, 512, 0, stream>>>(
        hidden, W_off, W_attn, b_off, b_attn, refp, vflat, tmp);

    // 3) out projection -> d_out f32
    out_proj<<<M / 32, 512, 0, stream>>>(tmp, W_out, b_out, out);
}

// Round 7
// 79.385 us; speedup vs baseline: 1.7103x; 1.7103x over previous
//
#include <hip/hip_runtime.h>

constexpr int HH = 100;
constexpr int WW = 100;
constexpr int NH = 8;
constexpr int NP = 4;
constexpr int B  = 4;
constexpr int Q  = HH * WW;   // 10000
constexpr int S  = Q;
constexpr int K  = 256;
constexpr int DH = 32;

typedef __attribute__((ext_vector_type(8))) short short8;
typedef __attribute__((ext_vector_type(4))) float f32x4;

struct __align__(8) ushort4_t { unsigned short x, y, z, w; };

__device__ inline unsigned short f2bf(float f) {
    unsigned u = __builtin_bit_cast(unsigned, f);
    u += 0x7fffu + ((u >> 16) & 1u);          // RNE
    return (unsigned short)(u >> 16);
}
__device__ inline float bf2f(unsigned short h) {
    return __builtin_bit_cast(float, ((unsigned)h) << 16);
}

// LDS bf16 tile helpers, XOR-swizzled (flips element-index bits 3..5 by row&7)
__device__ inline void lds_st16s(short* base, int row, int kcol, short8 v) {
    *reinterpret_cast<short8*>(&base[row * 64 + (kcol ^ ((row & 7) << 3))]) = v;
}
__device__ inline short8 lds_ld16s(const short* base, int row, int kcol) {
    return *reinterpret_cast<const short8*>(&base[row * 64 + (kcol ^ ((row & 7) << 3))]);
}

__device__ inline short8 cvt8(float4 a, float4 b) {
    short8 r;
    r[0] = (short)f2bf(a.x); r[1] = (short)f2bf(a.y);
    r[2] = (short)f2bf(a.z); r[3] = (short)f2bf(a.w);
    r[4] = (short)f2bf(b.x); r[5] = (short)f2bf(b.y);
    r[6] = (short)f2bf(b.z); r[7] = (short)f2bf(b.w);
    return r;
}

// ---------------------------------------------------------------------------
// Kernel A: value projection AND off/attn projection in ONE launch.
// Blocks 0..624    : enc[64 rows] @ W_val^T  -> vflat bf16  (tile 64x256)
// Blocks 625..1249 : hidden[64]  @ [W_off;W_attn]^T -> proj f32 [M][96]
// 512 threads = 8 waves. 1250 blocks -> ~4.9 blocks/CU demand (LDS cap 4).
// ---------------------------------------------------------------------------
__global__ __launch_bounds__(512) void dual_gemm(
    const float* __restrict__ enc, const float* __restrict__ Wval,
    const float* __restrict__ bval, unsigned short* __restrict__ vflat,
    const float* __restrict__ hidden, const float* __restrict__ Woff,
    const float* __restrict__ Wattn, const float* __restrict__ boff,
    const float* __restrict__ battn, float* __restrict__ proj)
{
    __shared__ short As[64 * 64];
    __shared__ short Bs[256 * 64];

    const int tid  = threadIdx.x;
    const int lane = tid & 63, w = tid >> 6;
    const int l15  = lane & 15, l4 = lane >> 4;
    const int srow = tid >> 3, sk8 = (tid & 7) * 8;

    if (blockIdx.x < 625) {
        // ---------------- value projection: 64 x 256 ----------------
        const int m0 = blockIdx.x * 64;
        const int n_base = w * 32;

        f32x4 acc[4][2];
#pragma unroll
        for (int i = 0; i < 4; ++i)
#pragma unroll
            for (int j = 0; j < 2; ++j) acc[i][j] = f32x4{0.f, 0.f, 0.f, 0.f};

        float4 fa0, fa1;
        float4 fb[4][2];
        auto ld = [&](int k0) {
            const float* s = &enc[(size_t)(m0 + srow) * K + k0 + sk8];
            fa0 = *reinterpret_cast<const float4*>(s);
            fa1 = *reinterpret_cast<const float4*>(s + 4);
#pragma unroll
            for (int i = 0; i < 4; ++i) {
                const float* ws = &Wval[(size_t)(srow + 64 * i) * K + k0 + sk8];
                fb[i][0] = *reinterpret_cast<const float4*>(ws);
                fb[i][1] = *reinterpret_cast<const float4*>(ws + 4);
            }
        };
        auto wr = [&]() {
            lds_st16s(As, srow, sk8, cvt8(fa0, fa1));
#pragma unroll
            for (int i = 0; i < 4; ++i)
                lds_st16s(Bs, srow + 64 * i, sk8, cvt8(fb[i][0], fb[i][1]));
        };

        ld(0);
        for (int k0 = 0; k0 < K; k0 += 64) {
            wr();
            __syncthreads();
            if (k0 < K - 64) ld(k0 + 64);
#pragma unroll
            for (int kk = 0; kk < 2; ++kk) {
                const int kc = kk * 32 + l4 * 8;
                short8 a[4];
#pragma unroll
                for (int mf = 0; mf < 4; ++mf)
                    a[mf] = lds_ld16s(As, mf * 16 + l15, kc);
#pragma unroll
                for (int nf = 0; nf < 2; ++nf) {
                    const short8 bv = lds_ld16s(Bs, n_base + nf * 16 + l15, kc);
#pragma unroll
                    for (int mf = 0; mf < 4; ++mf)
                        acc[mf][nf] = __builtin_amdgcn_mfma_f32_16x16x32_bf16(
                            a[mf], bv, acc[mf][nf], 0, 0, 0);
                }
            }
            __syncthreads();
        }

#pragma unroll
        for (int nf = 0; nf < 2; ++nf) {
            const int n = n_base + nf * 16 + l15;
            const float bias = bval[n];
            const int h = n >> 5, dd = n & 31;
#pragma unroll
            for (int mf = 0; mf < 4; ++mf)
#pragma unroll
                for (int r = 0; r < 4; ++r) {
                    const int m = m0 + mf * 16 + l4 * 4 + r;
                    const int b = m / S, s = m - (m / S) * S;
                    vflat[(((size_t)(b * NH + h)) * S + s) * DH + dd] =
                        f2bf(acc[mf][nf][r] + bias);
                }
        }
    } else {
        // ---------------- off+attn projection: 64 x 96 ----------------
        const int m0 = (blockIdx.x - 625) * 64;
        const int n_base = w * 16;   // waves 0..5 compute

        f32x4 acc[4];
#pragma unroll
        for (int i = 0; i < 4; ++i) acc[i] = f32x4{0.f, 0.f, 0.f, 0.f};

        float4 fa0, fa1;
        float4 fb[2][2];
        const int row1 = srow + 64;            // 64..127; valid if < 96
        auto ld = [&](int k0) {
            const float* s = &hidden[(size_t)(m0 + srow) * K + k0 + sk8];
            fa0 = *reinterpret_cast<const float4*>(s);
            fa1 = *reinterpret_cast<const float4*>(s + 4);
            const float* w0 = &Woff[(size_t)srow * K + k0 + sk8];
            fb[0][0] = *reinterpret_cast<const float4*>(w0);
            fb[0][1] = *reinterpret_cast<const float4*>(w0 + 4);
            if (row1 < 96) {
                const float* w1 = &Wattn[(size_t)(row1 - 64) * K + k0 + sk8];
                fb[1][0] = *reinterpret_cast<const float4*>(w1);
                fb[1][1] = *reinterpret_cast<const float4*>(w1 + 4);
            }
        };
        auto wr = [&]() {
            lds_st16s(As, srow, sk8, cvt8(fa0, fa1));
            lds_st16s(Bs, srow, sk8, cvt8(fb[0][0], fb[0][1]));
            if (row1 < 96) lds_st16s(Bs, row1, sk8, cvt8(fb[1][0], fb[1][1]));
        };

        ld(0);
        for (int k0 = 0; k0 < K; k0 += 64) {
            wr();
            __syncthreads();
            if (k0 < K - 64) ld(k0 + 64);
            if (w < 6) {
#pragma unroll
                for (int kk = 0; kk < 2; ++kk) {
                    const int kc = kk * 32 + l4 * 8;
                    const short8 bv = lds_ld16s(Bs, n_base + l15, kc);
#pragma unroll
                    for (int mf = 0; mf < 4; ++mf) {
                        const short8 a = lds_ld16s(As, mf * 16 + l15, kc);
                        acc[mf] = __builtin_amdgcn_mfma_f32_16x16x32_bf16(
                            a, bv, acc[mf], 0, 0, 0);
                    }
                }
            }
            __syncthreads();
        }
        if (w < 6) {
            const int col = n_base + l15;
            const float bias = (col < 64) ? boff[col] : battn[col - 64];
#pragma unroll
            for (int mf = 0; mf < 4; ++mf)
#pragma unroll
                for (int r = 0; r < 4; ++r) {
                    const int m = m0 + mf * 16 + l4 * 4 + r;
                    proj[(size_t)m * 96 + col] = acc[mf][r] + bias;
                }
        }
    }
}

// ---------------------------------------------------------------------------
// Kernel S: bilinear sampling + attention aggregation (round-4 version).
// 8 lanes per (b,h,q) group; lane owns 4 consecutive d-elements (ushort4).
// 32 groups per 256-thread block. XCD-swizzled for vflat L2 locality.
// ---------------------------------------------------------------------------
__global__ __launch_bounds__(256) void sample_agg(
    const unsigned short* __restrict__ vflat,  // [B*NH][S][DH] bf16
    const float* __restrict__ proj,            // [B*Q][96]
    const float* __restrict__ ref,             // [B*Q][2]
    unsigned short* __restrict__ tmp)          // [B*Q][256] bf16
{
    const int nblk = gridDim.x;
    const int cpx  = nblk >> 3;
    const int swz  = (blockIdx.x & 7) * cpx + (blockIdx.x >> 3);

    const int lg   = threadIdx.x >> 3;
    const int lane = threadIdx.x & 7;
    const int d0   = lane * 4;

    const int g  = swz * 32 + lg;
    const int q  = g % Q;
    const int bh = g / Q;
    const int b  = bh >> 3;
    const int h  = bh & 7;

    const size_t bq   = (size_t)b * Q + q;
    const float refx = ref[bq * 2 + 0];
    const float refy = ref[bq * 2 + 1];
    const float* pr = proj + bq * 96;

    float l[NP];
#pragma unroll
    for (int p = 0; p < NP; ++p) l[p] = pr[64 + h * 4 + p];
    const float mx = fmaxf(fmaxf(l[0], l[1]), fmaxf(l[2], l[3]));
    float e[NP];
    float esum = 0.f;
#pragma unroll
    for (int p = 0; p < NP; ++p) { e[p] = __expf(l[p] - mx); esum += e[p]; }
    const float inv = 1.f / esum;

    const unsigned short* vbase = vflat + (size_t)bh * (S * DH);

    int   cidx[NP][4];
    float cw[NP][4];
#pragma unroll
    for (int p = 0; p < NP; ++p) {
        const float ox = pr[h * 8 + p * 2 + 0];
        const float oy = pr[h * 8 + p * 2 + 1];
        const float x = (refx + ox * (1.0f / WW)) * WW - 0.5f;
        const float y = (refy + oy * (1.0f / HH)) * HH - 0.5f;
        const float x0f = floorf(x), y0f = floorf(y);
        const float wx1 = x - x0f, wx0 = 1.f - wx1;
        const float wy1 = y - y0f, wy0 = 1.f - wy1;
        const int x0 = (int)x0f, y0 = (int)y0f;
        const bool vx0 = (x0 >= 0) && (x0 < WW);
        const bool vx1 = (x0 + 1 >= 0) && (x0 + 1 < WW);
        const bool vy0 = (y0 >= 0) && (y0 < HH);
        const bool vy1 = (y0 + 1 >= 0) && (y0 + 1 < HH);
        const int xi0 = min(max(x0, 0), WW - 1);
        const int xi1 = min(max(x0 + 1, 0), WW - 1);
        const int yi0 = min(max(y0, 0), HH - 1);
        const int yi1 = min(max(y0 + 1, 0), HH - 1);
        const float ap = e[p] * inv;
        cw[p][0] = ap * wx0 * wy0 * ((vx0 && vy0) ? 1.f : 0.f);
        cw[p][1] = ap * wx1 * wy0 * ((vx1 && vy0) ? 1.f : 0.f);
        cw[p][2] = ap * wx0 * wy1 * ((vx0 && vy1) ? 1.f : 0.f);
        cw[p][3] = ap * wx1 * wy1 * ((vx1 && vy1) ? 1.f : 0.f);
        cidx[p][0] = (yi0 * WW + xi0) * DH + d0;
        cidx[p][1] = (yi0 * WW + xi1) * DH + d0;
        cidx[p][2] = (yi1 * WW + xi0) * DH + d0;
        cidx[p][3] = (yi1 * WW + xi1) * DH + d0;
    }

    float a0 = 0.f, a1 = 0.f, a2 = 0.f, a3 = 0.f;
#pragma unroll
    for (int p = 0; p < NP; ++p) {
#pragma unroll
        for (int c = 0; c < 4; ++c) {
            const ushort4_t v = *reinterpret_cast<const ushort4_t*>(&vbase[cidx[p][c]]);
            const float wgt = cw[p][c];
            a0 = fmaf(wgt, bf2f(v.x), a0);
            a1 = fmaf(wgt, bf2f(v.y), a1);
            a2 = fmaf(wgt, bf2f(v.z), a2);
            a3 = fmaf(wgt, bf2f(v.w), a3);
        }
    }

    ushort4_t o;
    o.x = f2bf(a0); o.y = f2bf(a1); o.z = f2bf(a2); o.w = f2bf(a3);
    *reinterpret_cast<ushort4_t*>(&tmp[bq * 256 + h * 32 + d0]) = o;
}

// ---------------------------------------------------------------------------
// Kernel O: out projection  tmp[M][256] bf16 @ W_out^T + b_out -> out f32.
// Tile 64 x 128 (N split in two halves) -> 1250 blocks, 24 KB LDS,
// 512 threads = 8 waves, each wave owns 64m x 16n.
// ---------------------------------------------------------------------------
__global__ __launch_bounds__(512) void out_proj(
    const unsigned short* __restrict__ tmp, const float* __restrict__ Wo,
    const float* __restrict__ bo, float* __restrict__ out)
{
    __shared__ short As[64 * 64];
    __shared__ short Bs[128 * 64];

    const int bid = blockIdx.x;
    const int m0  = (bid >> 1) * 64;
    const int n0  = (bid & 1) * 128;

    const int tid  = threadIdx.x;
    const int lane = tid & 63, w = tid >> 6;
    const int l15  = lane & 15, l4 = lane >> 4;
    const int srow = tid >> 3, sk8 = (tid & 7) * 8;

    f32x4 acc[4];
#pragma unroll
    for (int i = 0; i < 4; ++i) acc[i] = f32x4{0.f, 0.f, 0.f, 0.f};

    short8 sa;
    float4 fb[2][2];
    auto ld = [&](int k0) {
        sa = *reinterpret_cast<const short8*>(
            &tmp[(size_t)(m0 + srow) * K + k0 + sk8]);
#pragma unroll
        for (int i = 0; i < 2; ++i) {
            const float* ws = &Wo[(size_t)(n0 + srow + 64 * i) * K + k0 + sk8];
            fb[i][0] = *reinterpret_cast<const float4*>(ws);
            fb[i][1] = *reinterpret_cast<const float4*>(ws + 4);
        }
    };
    auto wr = [&]() {
        lds_st16s(As, srow, sk8, sa);
#pragma unroll
        for (int i = 0; i < 2; ++i)
            lds_st16s(Bs, srow + 64 * i, sk8, cvt8(fb[i][0], fb[i][1]));
    };

    ld(0);
    for (int k0 = 0; k0 < K; k0 += 64) {
        wr();
        __syncthreads();
        if (k0 < K - 64) ld(k0 + 64);
#pragma unroll
        for (int kk = 0; kk < 2; ++kk) {
            const int kc = kk * 32 + l4 * 8;
            const short8 bv = lds_ld16s(Bs, w * 16 + l15, kc);
#pragma unroll
            for (int mf = 0; mf < 4; ++mf) {
                const short8 a = lds_ld16s(As, mf * 16 + l15, kc);
                acc[mf] = __builtin_amdgcn_mfma_f32_16x16x32_bf16(
                    a, bv, acc[mf], 0, 0, 0);
            }
        }
        __syncthreads();
    }

    const int n = n0 + w * 16 + l15;
    const float bias = bo[n];
#pragma unroll
    for (int mf = 0; mf < 4; ++mf)
#pragma unroll
        for (int r = 0; r < 4; ++r) {
            const int m = m0 + mf * 16 + l4 * 4 + r;
            out[(size_t)m * K + n] = acc[mf][r] + bias;
        }
}

// ---------------------------------------------------------------------------
extern "C" void kernel_launch(void* const* d_in, const int* in_sizes, int n_in,
                              void* d_out, int out_size, void* d_ws, size_t ws_size,
                              hipStream_t stream)
{
    const float* hidden = (const float*)d_in[0];
    const float* enc    = (const float*)d_in[1];
    const float* refp   = (const float*)d_in[2];
    const float* W_off  = (const float*)d_in[4];
    const float* b_off  = (const float*)d_in[5];
    const float* W_attn = (const float*)d_in[6];
    const float* b_attn = (const float*)d_in[7];
    const float* W_val  = (const float*)d_in[8];
    const float* b_val  = (const float*)d_in[9];
    const float* W_out  = (const float*)d_in[10];
    const float* b_out  = (const float*)d_in[11];
    float* out = (float*)d_out;

    unsigned short* vflat = (unsigned short*)d_ws;                       // 20.48 MB
    float* proj = (float*)((char*)d_ws + (size_t)B * NH * S * DH * 2);   // 15.36 MB
    unsigned short* tmp = (unsigned short*)((char*)proj + (size_t)B * Q * 96 * 4);

    const int M = B * Q;  // 40000

    // 1) value proj (625 blocks) + off/attn proj (625 blocks) in one launch
    dual_gemm<<<1250, 512, 0, stream>>>(
        enc, W_val, b_val, vflat, hidden, W_off, W_attn, b_off, b_attn, proj);

    // 2) bilinear sampling + softmax aggregation -> tmp bf16 [M][256]
    sample_agg<<<(B * NH * Q) / 32, 256, 0, stream>>>(vflat, proj, refp, tmp);

    // 3) out projection (N split in halves -> 1250 blocks) -> d_out f32
    out_proj<<<1250, 512, 0, stream>>>(tmp, W_out, b_out, out);
}